// Round 1
// baseline (24991.731 us; speedup 1.0000x reference)
//
#include <hip/hip_runtime.h>
#include <hip/hip_bf16.h>

#define B 64
#define SEQ 256
#define IN 512
#define HD 1024
#define ODIM 512
#define NWG 64
#define WGTH 256

typedef __attribute__((ext_vector_type(8))) short bf16x8;
typedef __attribute__((ext_vector_type(4))) float f32x4;
typedef __attribute__((ext_vector_type(4))) unsigned short u16x4;

__device__ __forceinline__ f32x4 mfma16(bf16x8 a, bf16x8 b, f32x4 c) {
  return __builtin_amdgcn_mfma_f32_16x16x32_bf16(a, b, c, 0, 0, 0);
}

__device__ __forceinline__ unsigned short f2bf(float f) {
  unsigned u = __builtin_bit_cast(unsigned, f);
  u += 0x7FFFu + ((u >> 16) & 1u);
  return (unsigned short)(u >> 16);
}

__device__ __forceinline__ float sigmoidf_(float x) { return 1.f / (1.f + expf(-x)); }

__global__ void f32_to_bf16_k(const float* __restrict__ s, unsigned short* __restrict__ d, int n) {
  int i = (blockIdx.x * blockDim.x + threadIdx.x) * 4;
  if (i < n) {
    float4 v = *reinterpret_cast<const float4*>(s + i);
    u16x4 o;
    o.x = f2bf(v.x); o.y = f2bf(v.y); o.z = f2bf(v.z); o.w = f2bf(v.w);
    *reinterpret_cast<u16x4*>(d + i) = o;
  }
}

struct GruP {
  const unsigned short* xbf;        // [B][SEQ][IN]
  const unsigned short* wx[2][3];   // [layer][z,r,g]  rows n (HD), cols k (Kext)
  const unsigned short* wh[2][3];   // rows n (HD), cols k (HD)
  const float* bx[2][3];
  float* hf[2];                     // fp32 hidden state [B][HD]
  unsigned short* h0b[2];           // layer0 h (= y0[t]) bf16, parity double-buffer
  unsigned short* h1b;              // layer1 h bf16
  float* zf[2];                     // z gate fp32 [B][HD]
  unsigned short* rh[2];            // r*h bf16 [B][HD]
  unsigned short* y1;               // [B][SEQ][HD] bf16
  float* outh;                      // d_out + B*SEQ*ODIM : [B][2][HD]
  unsigned* bar;                    // barrier slots (zeroed each launch)
};

__device__ __forceinline__ void gbar(unsigned* slot) {
  __syncthreads();
  if (threadIdx.x == 0) {
    __threadfence();
    __hip_atomic_fetch_add(slot, 1u, __ATOMIC_RELEASE, __HIP_MEMORY_SCOPE_AGENT);
    while (__hip_atomic_load(slot, __ATOMIC_ACQUIRE, __HIP_MEMORY_SCOPE_AGENT) < NWG)
      __builtin_amdgcn_s_sleep(1);
    __threadfence();
  }
  __syncthreads();
}

__global__ __launch_bounds__(WGTH) void gru_persist(GruP P) {
  const int wg = blockIdx.x;
  const int layer = wg >> 5;            // 32 WGs per layer
  const int c0 = (wg & 31) * 32;        // 32-column slice of H
  const int tid = threadIdx.x;
  const int w = tid >> 6;               // wave 0..3 -> m-rows [16w,16w+16)
  const int lane = tid & 63;
  const int lo = lane & 15;
  const int hi = lane >> 4;
  const int Kext = layer ? HD : IN;
  const int bA = 16 * w + lo;           // A-frag row (batch) for loads
  const int koff = hi * 8;              // A/B frag k offset within 32-chunk

  const unsigned short* WXZ = P.wx[layer][0];
  const unsigned short* WXR = P.wx[layer][1];
  const unsigned short* WXG = P.wx[layer][2];
  const unsigned short* WHZ = P.wh[layer][0];
  const unsigned short* WHR = P.wh[layer][1];
  const unsigned short* WHG = P.wh[layer][2];
  const float* BXZ = P.bx[layer][0];
  const float* BXR = P.bx[layer][1];
  const float* BXG = P.bx[layer][2];
  float* HF = P.hf[layer];
  float* ZF = P.zf[layer];
  unsigned short* RH = P.rh[layer];

  for (int p = 0; p <= SEQ; ++p) {
    const int t = layer ? (p - 1) : p;
    const bool act = layer ? (p >= 1) : (p < SEQ);

    // ---------------- phase A: z, r ----------------
    if (act) {
      const unsigned short* aRow = layer
          ? P.h0b[t & 1] + bA * HD + koff
          : P.xbf + ((size_t)bA * SEQ + t) * IN + koff;
      const unsigned short* hRow = (layer ? P.h1b : P.h0b[(t + 1) & 1]) + bA * HD + koff;

      f32x4 az0 = {0.f,0.f,0.f,0.f}, az1 = {0.f,0.f,0.f,0.f};
      f32x4 ar0 = {0.f,0.f,0.f,0.f}, ar1 = {0.f,0.f,0.f,0.f};
      {
        const unsigned short* wz = WXZ + (size_t)(c0 + lo) * Kext + koff;
        const unsigned short* wr = WXR + (size_t)(c0 + lo) * Kext + koff;
        #pragma unroll 4
        for (int k = 0; k < Kext; k += 32) {
          bf16x8 a = *(const bf16x8*)(aRow + k);
          az0 = mfma16(a, *(const bf16x8*)(wz + k), az0);
          az1 = mfma16(a, *(const bf16x8*)(wz + 16 * Kext + k), az1);
          ar0 = mfma16(a, *(const bf16x8*)(wr + k), ar0);
          ar1 = mfma16(a, *(const bf16x8*)(wr + 16 * Kext + k), ar1);
        }
      }
      {
        const unsigned short* wz = WHZ + (size_t)(c0 + lo) * HD + koff;
        const unsigned short* wr = WHR + (size_t)(c0 + lo) * HD + koff;
        #pragma unroll 4
        for (int k = 0; k < HD; k += 32) {
          bf16x8 a = *(const bf16x8*)(hRow + k);
          az0 = mfma16(a, *(const bf16x8*)(wz + k), az0);
          az1 = mfma16(a, *(const bf16x8*)(wz + 16 * HD + k), az1);
          ar0 = mfma16(a, *(const bf16x8*)(wr + k), ar0);
          ar1 = mfma16(a, *(const bf16x8*)(wr + 16 * HD + k), ar1);
        }
      }
      {
        const int b0 = 16 * w + 4 * hi;
        const int cA = c0 + lo, cB = c0 + 16 + lo;
        const float bzA = BXZ[cA], bzB = BXZ[cB];
        const float brA = BXR[cA], brB = BXR[cB];
        #pragma unroll
        for (int q = 0; q < 4; ++q) {
          const int b = b0 + q;
          float z = sigmoidf_(az0[q] + bzA);
          float r = sigmoidf_(ar0[q] + brA);
          ZF[b * HD + cA] = z;
          RH[b * HD + cA] = f2bf(r * HF[b * HD + cA]);
          z = sigmoidf_(az1[q] + bzB);
          r = sigmoidf_(ar1[q] + brB);
          ZF[b * HD + cB] = z;
          RH[b * HD + cB] = f2bf(r * HF[b * HD + cB]);
        }
      }
    }
    gbar(P.bar + 2 * p);

    // ---------------- phase B: g, h-update ----------------
    if (act) {
      const unsigned short* aRow = layer
          ? P.h0b[t & 1] + bA * HD + koff
          : P.xbf + ((size_t)bA * SEQ + t) * IN + koff;
      const unsigned short* hRow = RH + bA * HD + koff;

      f32x4 ag0 = {0.f,0.f,0.f,0.f}, ag1 = {0.f,0.f,0.f,0.f};
      {
        const unsigned short* wg_ = WXG + (size_t)(c0 + lo) * Kext + koff;
        #pragma unroll 4
        for (int k = 0; k < Kext; k += 32) {
          bf16x8 a = *(const bf16x8*)(aRow + k);
          ag0 = mfma16(a, *(const bf16x8*)(wg_ + k), ag0);
          ag1 = mfma16(a, *(const bf16x8*)(wg_ + 16 * Kext + k), ag1);
        }
      }
      {
        const unsigned short* wg_ = WHG + (size_t)(c0 + lo) * HD + koff;
        #pragma unroll 4
        for (int k = 0; k < HD; k += 32) {
          bf16x8 a = *(const bf16x8*)(hRow + k);
          ag0 = mfma16(a, *(const bf16x8*)(wg_ + k), ag0);
          ag1 = mfma16(a, *(const bf16x8*)(wg_ + 16 * HD + k), ag1);
        }
      }
      {
        const int b0 = 16 * w + 4 * hi;
        const int cA = c0 + lo, cB = c0 + 16 + lo;
        const float bgA = BXG[cA], bgB = BXG[cB];
        #pragma unroll
        for (int q = 0; q < 4; ++q) {
          const int b = b0 + q;
          {
            float g = tanhf(ag0[q] + bgA);
            float z = ZF[b * HD + cA];
            float hv = HF[b * HD + cA];
            float hn = z * hv + (1.f - z) * g;
            HF[b * HD + cA] = hn;
            unsigned short hb = f2bf(hn);
            if (layer == 0) P.h0b[t & 1][b * HD + cA] = hb;
            else { P.h1b[b * HD + cA] = hb; P.y1[((size_t)b * SEQ + t) * HD + cA] = hb; }
            if (t == SEQ - 1) P.outh[(size_t)b * (2 * HD) + layer * HD + cA] = hn;
          }
          {
            float g = tanhf(ag1[q] + bgB);
            float z = ZF[b * HD + cB];
            float hv = HF[b * HD + cB];
            float hn = z * hv + (1.f - z) * g;
            HF[b * HD + cB] = hn;
            unsigned short hb = f2bf(hn);
            if (layer == 0) P.h0b[t & 1][b * HD + cB] = hb;
            else { P.h1b[b * HD + cB] = hb; P.y1[((size_t)b * SEQ + t) * HD + cB] = hb; }
            if (t == SEQ - 1) P.outh[(size_t)b * (2 * HD) + layer * HD + cB] = hn;
          }
        }
      }
    }
    gbar(P.bar + 2 * p + 1);
  }
}

// C[M=B*SEQ][ODIM] = Y[M][HD] @ W[ODIM][HD]^T + bias
__global__ __launch_bounds__(256) void out_gemm(const unsigned short* __restrict__ Y,
                                                const unsigned short* __restrict__ W,
                                                const float* __restrict__ bias,
                                                float* __restrict__ C) {
  const int w = threadIdx.x >> 6, lane = threadIdx.x & 63;
  const int lo = lane & 15, hi = lane >> 4;
  const int row0 = blockIdx.x * 64;
  const int col0 = blockIdx.y * 64 + w * 16;
  const unsigned short* wp = W + (size_t)(col0 + lo) * HD + hi * 8;
  const unsigned short* yp = Y + (size_t)(row0 + lo) * HD + hi * 8;
  f32x4 a0 = {0.f,0.f,0.f,0.f}, a1 = {0.f,0.f,0.f,0.f};
  f32x4 a2 = {0.f,0.f,0.f,0.f}, a3 = {0.f,0.f,0.f,0.f};
  #pragma unroll 4
  for (int k = 0; k < HD; k += 32) {
    bf16x8 bw = *(const bf16x8*)(wp + k);
    a0 = mfma16(*(const bf16x8*)(yp + k), bw, a0);
    a1 = mfma16(*(const bf16x8*)(yp + (size_t)16 * HD + k), bw, a1);
    a2 = mfma16(*(const bf16x8*)(yp + (size_t)32 * HD + k), bw, a2);
    a3 = mfma16(*(const bf16x8*)(yp + (size_t)48 * HD + k), bw, a3);
  }
  const int cc = col0 + lo;
  const float bb = bias[cc];
  const int rbase = row0 + 4 * hi;
  #pragma unroll
  for (int q = 0; q < 4; ++q) {
    C[(size_t)(rbase + q) * ODIM + cc]      = a0[q] + bb;
    C[(size_t)(rbase + 16 + q) * ODIM + cc] = a1[q] + bb;
    C[(size_t)(rbase + 32 + q) * ODIM + cc] = a2[q] + bb;
    C[(size_t)(rbase + 48 + q) * ODIM + cc] = a3[q] + bb;
  }
}

extern "C" void kernel_launch(void* const* d_in, const int* in_sizes, int n_in,
                              void* d_out, int out_size, void* d_ws, size_t ws_size,
                              hipStream_t stream) {
  char* ws = (char*)d_ws;
  size_t off = 0;
  auto take = [&](size_t bytes) -> char* {
    char* p = ws + off;
    off += (bytes + 255) & ~(size_t)255;
    return p;
  };

  unsigned short* xbf = (unsigned short*)take((size_t)B * SEQ * IN * 2);
  unsigned short *wx0[3], *wh0[3], *wx1[3], *wh1[3];
  for (int g = 0; g < 3; ++g) wx0[g] = (unsigned short*)take((size_t)HD * IN * 2);
  for (int g = 0; g < 3; ++g) wh0[g] = (unsigned short*)take((size_t)HD * HD * 2);
  for (int g = 0; g < 3; ++g) wx1[g] = (unsigned short*)take((size_t)HD * HD * 2);
  for (int g = 0; g < 3; ++g) wh1[g] = (unsigned short*)take((size_t)HD * HD * 2);
  unsigned short* whyb = (unsigned short*)take((size_t)ODIM * HD * 2);
  unsigned short* y1 = (unsigned short*)take((size_t)B * SEQ * HD * 2);
  char* state0 = ws + off;
  float* h0f = (float*)take((size_t)B * HD * 4);
  float* h1f = (float*)take((size_t)B * HD * 4);
  unsigned short* h0b0 = (unsigned short*)take((size_t)B * HD * 2);
  unsigned short* h0b1 = (unsigned short*)take((size_t)B * HD * 2);
  unsigned short* h1b  = (unsigned short*)take((size_t)B * HD * 2);
  float* z0 = (float*)take((size_t)B * HD * 4);
  float* z1 = (float*)take((size_t)B * HD * 4);
  unsigned short* rh0 = (unsigned short*)take((size_t)B * HD * 2);
  unsigned short* rh1 = (unsigned short*)take((size_t)B * HD * 2);
  unsigned* bar = (unsigned*)take(4096);
  size_t stateBytes = (size_t)((ws + off) - state0);

  auto conv = [&](const void* s, unsigned short* d, int n) {
    hipLaunchKernelGGL(f32_to_bf16_k, dim3((n / 4 + 255) / 256), dim3(256), 0, stream,
                       (const float*)s, d, n);
  };
  conv(d_in[0], xbf, B * SEQ * IN);
  conv(d_in[1], wx0[0], HD * IN);  conv(d_in[4], wx0[1], HD * IN);  conv(d_in[7], wx0[2], HD * IN);
  conv(d_in[3], wh0[0], HD * HD);  conv(d_in[6], wh0[1], HD * HD);  conv(d_in[9], wh0[2], HD * HD);
  conv(d_in[10], wx1[0], HD * HD); conv(d_in[13], wx1[1], HD * HD); conv(d_in[16], wx1[2], HD * HD);
  conv(d_in[12], wh1[0], HD * HD); conv(d_in[15], wh1[1], HD * HD); conv(d_in[18], wh1[2], HD * HD);
  conv(d_in[19], whyb, ODIM * HD);

  hipMemsetAsync(state0, 0, stateBytes, stream);

  GruP P;
  P.xbf = xbf;
  for (int g = 0; g < 3; ++g) {
    P.wx[0][g] = wx0[g]; P.wh[0][g] = wh0[g];
    P.wx[1][g] = wx1[g]; P.wh[1][g] = wh1[g];
  }
  P.bx[0][0] = (const float*)d_in[2];  P.bx[0][1] = (const float*)d_in[5];  P.bx[0][2] = (const float*)d_in[8];
  P.bx[1][0] = (const float*)d_in[11]; P.bx[1][1] = (const float*)d_in[14]; P.bx[1][2] = (const float*)d_in[17];
  P.hf[0] = h0f; P.hf[1] = h1f;
  P.h0b[0] = h0b0; P.h0b[1] = h0b1; P.h1b = h1b;
  P.zf[0] = z0; P.zf[1] = z1;
  P.rh[0] = rh0; P.rh[1] = rh1;
  P.y1 = y1;
  P.outh = (float*)d_out + (size_t)B * SEQ * ODIM;
  P.bar = bar;

  hipLaunchKernelGGL(gru_persist, dim3(NWG), dim3(WGTH), 0, stream, P);

  hipLaunchKernelGGL(out_gemm, dim3((B * SEQ) / 64, ODIM / 64), dim3(256), 0, stream,
                     (const unsigned short*)y1, (const unsigned short*)whyb,
                     (const float*)d_in[20], (float*)d_out);
}

// Round 2
// 15131.606 us; speedup vs baseline: 1.6516x; 1.6516x over previous
//
#include <hip/hip_runtime.h>
#include <hip/hip_bf16.h>

#define B 64
#define SEQ 256
#define IN 512
#define HD 1024
#define ODIM 512
#define NWG 64
#define WGTH 512

typedef __attribute__((ext_vector_type(8))) short bf16x8;
typedef __attribute__((ext_vector_type(4))) float f32x4;
typedef __attribute__((ext_vector_type(4))) unsigned short u16x4;

__device__ __forceinline__ f32x4 mfma16(bf16x8 a, bf16x8 b, f32x4 c) {
  return __builtin_amdgcn_mfma_f32_16x16x32_bf16(a, b, c, 0, 0, 0);
}

__device__ __forceinline__ unsigned short f2bf(float f) {
  unsigned u = __builtin_bit_cast(unsigned, f);
  u += 0x7FFFu + ((u >> 16) & 1u);
  return (unsigned short)(u >> 16);
}

__device__ __forceinline__ float sigmoidf_(float x) { return 1.f / (1.f + expf(-x)); }

// ---- x: plain f32 -> bf16 conversion (A-operand, row-major kept) ----
__global__ void f32_to_bf16_k(const float* __restrict__ s, unsigned short* __restrict__ d, int n) {
  int i = (blockIdx.x * blockDim.x + threadIdx.x) * 4;
  if (i < n) {
    float4 v = *reinterpret_cast<const float4*>(s + i);
    u16x4 o;
    o.x = f2bf(v.x); o.y = f2bf(v.y); o.z = f2bf(v.z); o.w = f2bf(v.w);
    *reinterpret_cast<u16x4*>(d + i) = o;
  }
}

// ---- weights: f32 [N][K] -> bf16 packed MFMA B-fragment layout ----
// packed offset = (ntile*(K/32)+kchunk)*512 + lane*8 + j
// n = ntile*16 + (lane&15), k = kchunk*32 + (lane>>4)*8 + j
struct PackSeg { const float* s; unsigned short* d; int N; int K; };
struct PackP { PackSeg seg[13]; };

__global__ void pack_w(PackP P) {
  PackSeg sg = P.seg[blockIdx.y];
  const int kc_n = sg.K >> 5;
  const int total = (sg.N * sg.K) >> 3;
  for (int i = blockIdx.x * blockDim.x + threadIdx.x; i < total; i += gridDim.x * blockDim.x) {
    int lane = i & 63;
    int block = i >> 6;
    int kc = block % kc_n;
    int nt = block / kc_n;
    int n = nt * 16 + (lane & 15);
    int k = kc * 32 + (lane >> 4) * 8;
    const float* s = sg.s + (size_t)n * sg.K + k;
    float4 v0 = *(const float4*)(s);
    float4 v1 = *(const float4*)(s + 4);
    u16x4 o0, o1;
    o0.x = f2bf(v0.x); o0.y = f2bf(v0.y); o0.z = f2bf(v0.z); o0.w = f2bf(v0.w);
    o1.x = f2bf(v1.x); o1.y = f2bf(v1.y); o1.z = f2bf(v1.z); o1.w = f2bf(v1.w);
    unsigned short* dp = sg.d + (size_t)i * 8;
    *(u16x4*)(dp) = o0;
    *(u16x4*)(dp + 4) = o1;
  }
}

struct GruP {
  const unsigned short* xbf;        // [B][SEQ][IN] bf16 row-major
  const unsigned short* wx[2][3];   // packed frag layout, K = IN (L0) / HD (L1)
  const unsigned short* wh[2][3];   // packed frag layout, K = HD
  const float* bx[2][3];
  unsigned short* h0b[2];           // layer0 h bf16, parity double-buffer
  unsigned short* h1b;              // layer1 h bf16
  unsigned short* rh[2];            // r*h bf16 [B][HD]
  unsigned short* y1;               // [B][SEQ][HD] bf16
  float* outh;                      // d_out + B*SEQ*ODIM : [B][2][HD]
  unsigned* bar;                    // barrier region (zeroed each launch)
};

// two-level sense barrier: 8 groups x 8 WGs, per-phase slots (1KB stride)
__device__ __forceinline__ void gbar(unsigned* bar, int p, int wg) {
  __syncthreads();
  if (threadIdx.x == 0) {
    unsigned* base = bar + (size_t)p * 256;       // 256 uints = 1KB per phase
    unsigned* grp  = base + (wg >> 3) * 16;       // 64B apart
    unsigned* root = base + 8 * 16;
    unsigned* flag = base + 9 * 16;
    unsigned old = __hip_atomic_fetch_add(grp, 1u, __ATOMIC_ACQ_REL, __HIP_MEMORY_SCOPE_AGENT);
    if (old == 7u) {
      unsigned r = __hip_atomic_fetch_add(root, 1u, __ATOMIC_ACQ_REL, __HIP_MEMORY_SCOPE_AGENT);
      if (r == 7u)
        __hip_atomic_store(flag, 1u, __ATOMIC_RELEASE, __HIP_MEMORY_SCOPE_AGENT);
    }
    while (__hip_atomic_load(flag, __ATOMIC_RELAXED, __HIP_MEMORY_SCOPE_AGENT) == 0u)
      __builtin_amdgcn_s_sleep(1);
    (void)__hip_atomic_load(flag, __ATOMIC_ACQUIRE, __HIP_MEMORY_SCOPE_AGENT);
  }
  __syncthreads();
}

__global__ __launch_bounds__(WGTH) void gru_persist(GruP P) {
  const int wg = blockIdx.x;
  const int layer = wg >> 5;            // 32 WGs per layer
  const int c0 = (wg & 31) * 32;        // 32-column slice of H
  const int tid = threadIdx.x;
  const int w = tid >> 6;               // 8 waves
  const int lane = tid & 63;
  const int lo = lane & 15;
  const int hi = lane >> 4;
  const int mw = w & 3;                 // m-tile: batch rows [16mw,16mw+16)
  const int nw = w >> 2;                // n-tile: cols [c0+16nw, +16)
  const int Kx = layer ? HD : IN;
  const int bA = 16 * mw + lo;          // A-frag row (batch)
  const int koff = hi * 8;
  const int cC = c0 + nw * 16 + lo;     // this lane's output column
  const int nt = (c0 >> 4) + nw;        // weight n-tile index (wave-uniform)

  // packed weight fragment pointers: uniform base + lane*8; advance 512/chunk
  const unsigned short* WXZ = P.wx[layer][0] + ((size_t)nt * (Kx >> 5)) * 512 + (size_t)lane * 8;
  const unsigned short* WXR = P.wx[layer][1] + ((size_t)nt * (Kx >> 5)) * 512 + (size_t)lane * 8;
  const unsigned short* WXG = P.wx[layer][2] + ((size_t)nt * (Kx >> 5)) * 512 + (size_t)lane * 8;
  const unsigned short* WHZ = P.wh[layer][0] + ((size_t)nt * (HD >> 5)) * 512 + (size_t)lane * 8;
  const unsigned short* WHR = P.wh[layer][1] + ((size_t)nt * (HD >> 5)) * 512 + (size_t)lane * 8;
  const unsigned short* WHG = P.wh[layer][2] + ((size_t)nt * (HD >> 5)) * 512 + (size_t)lane * 8;
  const float bz = P.bx[layer][0][cC];
  const float br = P.bx[layer][1][cC];
  const float bg = P.bx[layer][2][cC];
  unsigned short* RH = P.rh[layer];
  const int b0 = 16 * mw + 4 * hi;

  f32x4 hreg = {0.f, 0.f, 0.f, 0.f};   // h tile, fp32, lives in regs
  f32x4 zreg = {0.f, 0.f, 0.f, 0.f};   // z gate carried phase A -> B

  for (int p = 0; p <= SEQ; ++p) {
    const int t = layer ? (p - 1) : p;
    const bool act = layer ? (p >= 1) : (p < SEQ);

    // ---------------- phase A: z, r ----------------
    if (act) {
      const unsigned short* aX = (layer ? P.h0b[t & 1] + (size_t)bA * HD
                                        : P.xbf + ((size_t)bA * SEQ + t) * IN) + koff;
      const unsigned short* aH = (layer ? P.h1b : P.h0b[(t + 1) & 1]) + (size_t)bA * HD + koff;
      f32x4 az = {0.f,0.f,0.f,0.f}, ar = {0.f,0.f,0.f,0.f};
      #pragma unroll 4
      for (int kb = 0; kb < (Kx >> 5); ++kb) {
        bf16x8 a = *(const bf16x8*)(aX + kb * 32);
        az = mfma16(a, *(const bf16x8*)(WXZ + kb * 512), az);
        ar = mfma16(a, *(const bf16x8*)(WXR + kb * 512), ar);
      }
      #pragma unroll 4
      for (int kb = 0; kb < (HD >> 5); ++kb) {
        bf16x8 a = *(const bf16x8*)(aH + kb * 32);
        az = mfma16(a, *(const bf16x8*)(WHZ + kb * 512), az);
        ar = mfma16(a, *(const bf16x8*)(WHR + kb * 512), ar);
      }
      #pragma unroll
      for (int q = 0; q < 4; ++q) {
        float z = sigmoidf_(az[q] + bz);
        float r = sigmoidf_(ar[q] + br);
        zreg[q] = z;
        RH[(size_t)(b0 + q) * HD + cC] = f2bf(r * hreg[q]);
      }
    }
    gbar(P.bar, 2 * p, wg);

    // ---------------- phase B: g, h-update ----------------
    if (act) {
      const unsigned short* aX = (layer ? P.h0b[t & 1] + (size_t)bA * HD
                                        : P.xbf + ((size_t)bA * SEQ + t) * IN) + koff;
      const unsigned short* aR = RH + (size_t)bA * HD + koff;
      f32x4 ag = {0.f,0.f,0.f,0.f};
      #pragma unroll 4
      for (int kb = 0; kb < (Kx >> 5); ++kb)
        ag = mfma16(*(const bf16x8*)(aX + kb * 32), *(const bf16x8*)(WXG + kb * 512), ag);
      #pragma unroll 4
      for (int kb = 0; kb < (HD >> 5); ++kb)
        ag = mfma16(*(const bf16x8*)(aR + kb * 32), *(const bf16x8*)(WHG + kb * 512), ag);
      unsigned short* hb = layer ? P.h1b : P.h0b[t & 1];
      #pragma unroll
      for (int q = 0; q < 4; ++q) {
        float g = tanhf(ag[q] + bg);
        float hn = zreg[q] * hreg[q] + (1.f - zreg[q]) * g;
        hreg[q] = hn;
        unsigned short hv = f2bf(hn);
        hb[(size_t)(b0 + q) * HD + cC] = hv;
        if (layer) P.y1[(((size_t)(b0 + q)) * SEQ + t) * HD + cC] = hv;
      }
      if (t == SEQ - 1) {
        #pragma unroll
        for (int q = 0; q < 4; ++q)
          P.outh[(size_t)(b0 + q) * (2 * HD) + layer * HD + cC] = hreg[q];
      }
    }
    gbar(P.bar, 2 * p + 1, wg);
  }
}

// C[M=B*SEQ][ODIM] = Y[M][HD] @ Wp(packed)[ODIM][HD]^T + bias
__global__ __launch_bounds__(256) void out_gemm(const unsigned short* __restrict__ Y,
                                                const unsigned short* __restrict__ Wp,
                                                const float* __restrict__ bias,
                                                float* __restrict__ C) {
  const int w = threadIdx.x >> 6, lane = threadIdx.x & 63;
  const int lo = lane & 15, hi = lane >> 4;
  const int row0 = blockIdx.x * 64;
  const int col0 = blockIdx.y * 64 + w * 16;
  const unsigned short* wp = Wp + ((size_t)(col0 >> 4) * (HD >> 5)) * 512 + (size_t)lane * 8;
  const unsigned short* yp = Y + (size_t)(row0 + lo) * HD + hi * 8;
  f32x4 a0 = {0.f,0.f,0.f,0.f}, a1 = {0.f,0.f,0.f,0.f};
  f32x4 a2 = {0.f,0.f,0.f,0.f}, a3 = {0.f,0.f,0.f,0.f};
  #pragma unroll 4
  for (int kb = 0; kb < (HD >> 5); ++kb) {
    bf16x8 bw = *(const bf16x8*)(wp + kb * 512);
    const int k = kb * 32;
    a0 = mfma16(*(const bf16x8*)(yp + k), bw, a0);
    a1 = mfma16(*(const bf16x8*)(yp + (size_t)16 * HD + k), bw, a1);
    a2 = mfma16(*(const bf16x8*)(yp + (size_t)32 * HD + k), bw, a2);
    a3 = mfma16(*(const bf16x8*)(yp + (size_t)48 * HD + k), bw, a3);
  }
  const int cc = col0 + lo;
  const float bb = bias[cc];
  const int rbase = row0 + 4 * hi;
  #pragma unroll
  for (int q = 0; q < 4; ++q) {
    C[(size_t)(rbase + q) * ODIM + cc]      = a0[q] + bb;
    C[(size_t)(rbase + 16 + q) * ODIM + cc] = a1[q] + bb;
    C[(size_t)(rbase + 32 + q) * ODIM + cc] = a2[q] + bb;
    C[(size_t)(rbase + 48 + q) * ODIM + cc] = a3[q] + bb;
  }
}

extern "C" void kernel_launch(void* const* d_in, const int* in_sizes, int n_in,
                              void* d_out, int out_size, void* d_ws, size_t ws_size,
                              hipStream_t stream) {
  char* ws = (char*)d_ws;
  size_t off = 0;
  auto take = [&](size_t bytes) -> char* {
    char* p = ws + off;
    off += (bytes + 255) & ~(size_t)255;
    return p;
  };

  unsigned short* xbf = (unsigned short*)take((size_t)B * SEQ * IN * 2);
  unsigned short *wx0[3], *wh0[3], *wx1[3], *wh1[3];
  for (int g = 0; g < 3; ++g) wx0[g] = (unsigned short*)take((size_t)HD * IN * 2);
  for (int g = 0; g < 3; ++g) wh0[g] = (unsigned short*)take((size_t)HD * HD * 2);
  for (int g = 0; g < 3; ++g) wx1[g] = (unsigned short*)take((size_t)HD * HD * 2);
  for (int g = 0; g < 3; ++g) wh1[g] = (unsigned short*)take((size_t)HD * HD * 2);
  unsigned short* whyb = (unsigned short*)take((size_t)ODIM * HD * 2);
  unsigned short* y1 = (unsigned short*)take((size_t)B * SEQ * HD * 2);
  char* state0 = ws + off;
  unsigned short* h0b0 = (unsigned short*)take((size_t)B * HD * 2);
  unsigned short* h0b1 = (unsigned short*)take((size_t)B * HD * 2);
  unsigned short* h1b  = (unsigned short*)take((size_t)B * HD * 2);
  unsigned short* rh0 = (unsigned short*)take((size_t)B * HD * 2);
  unsigned short* rh1 = (unsigned short*)take((size_t)B * HD * 2);
  unsigned* bar = (unsigned*)take((size_t)514 * 256 * 4);
  size_t stateBytes = (size_t)((ws + off) - state0);

  // x conversion (row-major bf16)
  {
    int n = B * SEQ * IN;
    hipLaunchKernelGGL(f32_to_bf16_k, dim3((n / 4 + 255) / 256), dim3(256), 0, stream,
                       (const float*)d_in[0], xbf, n);
  }

  // pack all 13 weight matrices into MFMA fragment layout (f32->bf16 fused)
  {
    PackP pp;
    int s = 0;
    pp.seg[s++] = { (const float*)d_in[1],  wx0[0], HD, IN };
    pp.seg[s++] = { (const float*)d_in[4],  wx0[1], HD, IN };
    pp.seg[s++] = { (const float*)d_in[7],  wx0[2], HD, IN };
    pp.seg[s++] = { (const float*)d_in[3],  wh0[0], HD, HD };
    pp.seg[s++] = { (const float*)d_in[6],  wh0[1], HD, HD };
    pp.seg[s++] = { (const float*)d_in[9],  wh0[2], HD, HD };
    pp.seg[s++] = { (const float*)d_in[10], wx1[0], HD, HD };
    pp.seg[s++] = { (const float*)d_in[13], wx1[1], HD, HD };
    pp.seg[s++] = { (const float*)d_in[16], wx1[2], HD, HD };
    pp.seg[s++] = { (const float*)d_in[12], wh1[0], HD, HD };
    pp.seg[s++] = { (const float*)d_in[15], wh1[1], HD, HD };
    pp.seg[s++] = { (const float*)d_in[18], wh1[2], HD, HD };
    pp.seg[s++] = { (const float*)d_in[19], whyb, ODIM, HD };
    hipLaunchKernelGGL(pack_w, dim3(512, 13), dim3(256), 0, stream, pp);
  }

  hipMemsetAsync(state0, 0, stateBytes, stream);

  GruP P;
  P.xbf = xbf;
  for (int g = 0; g < 3; ++g) {
    P.wx[0][g] = wx0[g]; P.wh[0][g] = wh0[g];
    P.wx[1][g] = wx1[g]; P.wh[1][g] = wh1[g];
  }
  P.bx[0][0] = (const float*)d_in[2];  P.bx[0][1] = (const float*)d_in[5];  P.bx[0][2] = (const float*)d_in[8];
  P.bx[1][0] = (const float*)d_in[11]; P.bx[1][1] = (const float*)d_in[14]; P.bx[1][2] = (const float*)d_in[17];
  P.h0b[0] = h0b0; P.h0b[1] = h0b1; P.h1b = h1b;
  P.rh[0] = rh0; P.rh[1] = rh1;
  P.y1 = y1;
  P.outh = (float*)d_out + (size_t)B * SEQ * ODIM;
  P.bar = bar;

  hipLaunchKernelGGL(gru_persist, dim3(NWG), dim3(WGTH), 0, stream, P);

  hipLaunchKernelGGL(out_gemm, dim3((B * SEQ) / 64, ODIM / 64), dim3(256), 0, stream,
                     (const unsigned short*)y1, (const unsigned short*)whyb,
                     (const float*)d_in[20], (float*)d_out);
}